// Round 13
// baseline (113.937 us; speedup 1.0000x reference)
//
#include <hip/hip_runtime.h>
#include <math.h>

#define PMAX 22
#define HID 64
#define OUTD 128
#define SETS_PER_WAVE 8
#define WAVES_PER_BLOCK 4
#define GROUPS 2  // set-groups per block (block-internal loop)

typedef __attribute__((ext_vector_type(4))) float float4v;
typedef _Float16 fh2 __attribute__((ext_vector_type(2)));
typedef _Float16 half8 __attribute__((ext_vector_type(8)));

__device__ __forceinline__ int rl_i(int v, int l) {
    return __builtin_amdgcn_readlane(v, l);
}
// pack two fp32 -> f16x2 bits (v_cvt_pkrtz_f16_f32)
__device__ __forceinline__ int pk2(float x, float y) {
    auto v = __builtin_amdgcn_cvt_pkrtz(x, y);
    union { decltype(v) h; int i; } c;
    c.h = v;
    return c.i;
}
// fp32 -> f16 bits (low half of pkrtz)
__device__ __forceinline__ unsigned short f16b(float x) {
    return (unsigned short)(pk2(x, x) & 0xFFFF);
}
// f16x2 dot-product accumulate: c += a.x*b.x + a.y*b.y (v_dot2_f32_f16)
__device__ __forceinline__ float fdot2i(int a, int b, float c) {
    union { int i; fh2 h; } ua, ub;
    ua.i = a;
    ub.i = b;
#if defined(__has_builtin) && __has_builtin(__builtin_amdgcn_fdot2)
    return __builtin_amdgcn_fdot2(ua.h, ub.h, c, false);
#else
    return fmaf((float)ua.h.x, (float)ub.h.x, fmaf((float)ua.h.y, (float)ub.h.y, c));
#endif
}
// Wave-internal LDS sync (per-wave hb slice only).
__device__ __forceinline__ void wave_lds_sync() {
    asm volatile("s_waitcnt lgkmcnt(0)" ::: "memory");
    __builtin_amdgcn_wave_barrier();
}
// Fast atan2: |err| ~1e-4 rad. Degree-7 odd minimax on [0,1].
__device__ __forceinline__ float fast_atan2(float y, float x) {
    float ax = fabsf(x), ay = fabsf(y);
    float mn = fminf(ax, ay), mx = fmaxf(ax, ay);
    float a = mn * __builtin_amdgcn_rcpf(fmaxf(mx, 1e-30f));
    float s = a * a;
    float r = a * fmaf(s, fmaf(s, fmaf(s, -0.0851330f, 0.1801410f), -0.3302995f), 0.9998660f);
    if (ay > ax) r = 1.57079637f - r;
    if (x < 0.0f) r = 3.14159274f - r;
    return copysignf(r, y);
}

__global__ __launch_bounds__(256) void set_encoder_kernel(
    const float* __restrict__ player_locs,  // [B,22,2]
    const float* __restrict__ actor_locs,   // [B,2]
    const float* __restrict__ flags,        // [B,22,2]
    const int*   __restrict__ mask,         // [B,22]
    const float* __restrict__ W1,           // [6,64]
    const float* __restrict__ b1,           // [64]
    const float* __restrict__ W2,           // [64,128]
    const float* __restrict__ b2,           // [128]
    float* __restrict__ out)                // [B,128]
{
    // B-fragments of W2 as f16 pairs (one ds_read_b128 per lane/frag).
    __shared__ __align__(16) unsigned w2f[16 * 256];                        // 16 KB
    // h-bar f16, [wave][set][hid]; 72-short row (144B) keeps b128 aligned.
    __shared__ __align__(16) unsigned short hb[WAVES_PER_BLOCK][SETS_PER_WAVE][72];

    const int tid  = threadIdx.x;
    const int lane = tid & 63;
    const int wave = tid >> 6;

    // Block owns 64 contiguous sets; each wave owns 16 (2 iterations of 8).
    const int wave_set_base =
        blockIdx.x * (WAVES_PER_BLOCK * SETS_PER_WAVE * GROUPS) +
        wave * (SETS_PER_WAVE * GROUPS);

    // --- W2 -> LDS B-fragments, f16 (block-cooperative, ONCE per block) ---
    {
        const int pr = tid >> 3;   // k-pair 0..31 (rows 2pr, 2pr+1)
        const int nt = tid & 7;    // n-tile 0..7
        const float* rA = W2 + (size_t)(2 * pr) * OUTD + 16 * nt;
        const float* rB = rA + OUTD;
        float ra[16], rb[16];
#pragma unroll
        for (int i = 0; i < 4; ++i) {
            *(float4*)&ra[4 * i] = ((const float4*)rA)[i];
            *(float4*)&rb[4 * i] = ((const float4*)rB)[i];
        }
        const int kt = pr >> 4;
        const int kk = (2 * pr) & 31;
        const int Q  = kk >> 3;
        const int j2 = (kk >> 1) & 3;
        const int base = ((kt * 8 + nt) * 4 + Q) * 64 + j2;
#pragma unroll
        for (int c = 0; c < 16; ++c)
            w2f[base + 4 * c] = pk2(ra[c], rb[c]);  // (k even, k odd) f16 pair
    }

    // --- per-lane W1 column + bias, packed f16x2 (lane = hidden unit) ---
    const int w01 = pk2(W1[0 * HID + lane], W1[1 * HID + lane]);
    const int w23 = pk2(W1[2 * HID + lane], W1[3 * HID + lane]);
    const int w45 = pk2(W1[4 * HID + lane], W1[5 * HID + lane]);
    const float b1l = b1[lane];

    __syncthreads();  // w2f visible to all waves (only block barrier)

    const int lidx  = lane < 2 * PMAX ? lane : 2 * PMAX - 1;  // clamp
    const int acoff = (lidx >= PMAX ? 1 : 0);

    // Double-buffered input registers: iteration it+1's loads issue during
    // iteration it's compute, hiding global-load latency.
    float2 pl[2][4], fl[2][4], ac[2][4];
    int    mk[2][4];
    auto load_group = [&](int it, int buf) {
        const int s0 = wave_set_base + it * SETS_PER_WAVE;
        const size_t r0 = (size_t)s0 * PMAX + lidx;
        const float2* plb = (const float2*)player_locs + r0;
        const float2* flb = (const float2*)flags + r0;
        const int*    mkb = mask + r0;
        const float2* acb = (const float2*)actor_locs + s0 + acoff;
#pragma unroll
        for (int g = 0; g < 4; ++g) {
            pl[buf][g] = plb[g * 2 * PMAX];
            fl[buf][g] = flb[g * 2 * PMAX];
            mk[buf][g] = mkb[g * 2 * PMAX];
            ac[buf][g] = acb[2 * g];
        }
    };
    load_group(0, 0);

    const int Q   = lane >> 4;
    const int c15 = lane & 15;
    const int sA  = lane & 7;
    const float* b2b = b2 + c15;
    float b2v[8];
#pragma unroll
    for (int nt = 0; nt < 8; ++nt) b2v[nt] = b2b[16 * nt];

#pragma unroll
    for (int it = 0; it < GROUPS; ++it) {
        const int buf = it & 1;
        if (it + 1 < GROUPS) load_group(it + 1, buf ^ 1);  // prefetch next iter

        const int set0 = wave_set_base + it * SETS_PER_WAVE;

        // --- phase 0: features into f16x2 regs; uniform validity bitmaps ---
        int fh[4][3];
        unsigned long long wbm[4];
#pragma unroll
        for (int g = 0; g < 4; ++g) {
            float dx = pl[buf][g].x - ac[buf][g].x;
            float dy = pl[buf][g].y - ac[buf][g].y;
            float dist = __builtin_amdgcn_sqrtf(fmaf(dx, dx, dy * dy));
            float ang  = fast_atan2(dy, dx);
            fh[g][0] = pk2(dx, dy);
            fh[g][1] = pk2(dist, ang);
            fh[g][2] = pk2(fl[buf][g].x, fl[buf][g].y);
            unsigned long long bl = __ballot((lane < 2 * PMAX) && (mk[buf][g] != 0));
            const unsigned lo = __builtin_amdgcn_readfirstlane((unsigned)bl);
            const unsigned hi = __builtin_amdgcn_readfirstlane((unsigned)(bl >> 32));
            wbm[g] = ((unsigned long long)hi << 32) | lo;  // uniform (SGPR pair)
        }

        // --- phase 1: layer1 + masked pool; lane = hidden unit; uniform
        //     scalar-branch unrolled p-loop, immediate readlane indices ---
        unsigned nonempty = 0;
#pragma unroll
        for (int s = 0; s < SETS_PER_WAVE; ++s) {
            const int g    = s >> 1;
            const int base = (s & 1) * PMAX;
            const unsigned bits = (unsigned)(wbm[g] >> base) & 0x3FFFFFu;
            const int cnt = __builtin_popcount(bits);
            if (bits) nonempty |= (1u << s);
            float acc = 0.0f;
#pragma unroll
            for (int p = 0; p < PMAX; ++p) {
                if (bits & (1u << p)) {
                    float t = fdot2i(rl_i(fh[g][0], base + p), w01, b1l);
                    t = fdot2i(rl_i(fh[g][1], base + p), w23, t);
                    t = fdot2i(rl_i(fh[g][2], base + p), w45, t);
                    acc += fmaxf(t, 0.0f);
                }
            }
            const float hbar = acc * (1.0f / fmaxf((float)cnt, 1.0f));
            hb[wave][s][lane] = f16b(hbar);
        }
        wave_lds_sync();

        // --- phase 2: out[8 sets x 128] = hbar @ W2 via f16 MFMA ---
        half8 afrag[2];
#pragma unroll
        for (int kt = 0; kt < 2; ++kt) {
            union { uint4 u4; half8 h8; } cv;
            cv.u4 = *(const uint4*)&hb[wave][sA][kt * 32 + Q * 8];  // aligned b128
            afrag[kt] = cv.h8;
        }

        float4v acc[8];
#pragma unroll
        for (int nt = 0; nt < 8; ++nt) {
            union { uint4 u4; half8 h8; } f0, f1;
            f0.u4 = *(const uint4*)&w2f[(0 * 8 + nt) * 256 + 4 * lane];
            f1.u4 = *(const uint4*)&w2f[(1 * 8 + nt) * 256 + 4 * lane];
            float4v z = {0.0f, 0.0f, 0.0f, 0.0f};
            acc[nt] = __builtin_amdgcn_mfma_f32_16x16x32_f16(afrag[0], f0.h8, z, 0, 0, 0);
            acc[nt] = __builtin_amdgcn_mfma_f32_16x16x32_f16(afrag[1], f1.h8, acc[nt], 0, 0, 0);
        }

        // --- epilogue: + b2 * [cnt>0]; C row=4Q+r (=set for Q<2), col=c15 ---
        if (Q < 2) {
            float fs[4];
#pragma unroll
            for (int r = 0; r < 4; ++r) fs[r] = (float)((nonempty >> (4 * Q + r)) & 1u);

            float* obase = out + (size_t)(set0 + 4 * Q) * OUTD + c15;
#pragma unroll
            for (int nt = 0; nt < 8; ++nt) {
#pragma unroll
                for (int r = 0; r < 4; ++r)
                    obase[r * OUTD + nt * 16] = fmaf(fs[r], b2v[nt], acc[nt][r]);
            }
        }
        // WAR on hb across iterations is safe: afrag's lgkmcnt-waited reads
        // complete before the next iteration's ds_writes issue (program order).
    }
}

extern "C" void kernel_launch(void* const* d_in, const int* in_sizes, int n_in,
                              void* d_out, int out_size, void* d_ws, size_t ws_size,
                              hipStream_t stream) {
    const float* player_locs = (const float*)d_in[0];
    const float* actor_locs  = (const float*)d_in[1];
    const float* flags       = (const float*)d_in[2];
    const int*   mask        = (const int*)d_in[3];
    const float* W1          = (const float*)d_in[4];
    const float* b1          = (const float*)d_in[5];
    const float* W2          = (const float*)d_in[6];
    const float* b2          = (const float*)d_in[7];
    float*       out         = (float*)d_out;

    const int B = in_sizes[0] / (PMAX * 2);  // 65536
    const int sets_per_block = WAVES_PER_BLOCK * SETS_PER_WAVE * GROUPS;  // 64
    const int grid = (B + sets_per_block - 1) / sets_per_block;           // 1024

    hipLaunchKernelGGL(set_encoder_kernel, dim3(grid), dim3(256), 0, stream,
                       player_locs, actor_locs, flags, mask, W1, b1, W2, b2, out);
}